// Round 3
// baseline (1062.588 us; speedup 1.0000x reference)
//
#include <hip/hip_runtime.h>
#include <stdint.h>

// MinGRUBlock on MI355X (gfx950). Input/output dtype (f32 vs bf16) DETECTED at
// runtime from x's bit patterns (flag in ws). Internals bf16. Residual in ws.
// Small GEMMs: mfma_f32_16x16x32_bf16, 128x128 tile, BK=64, global_load_lds
// w=16, XOR-swizzled LDS (chunk c of row r at c^(r&7)).
// Big GEMMs (FF gate/value and FF out): 256x256 tile, 8 waves, 4-phase-per-tile
// schedule, ONE barrier per phase, 1-phase REGISTER SOFTWARE PIPELINE (each
// phase's ds_reads feed the NEXT phase's MFMA and are issued after this
// phase's MFMA cluster -> LDS pipe overlaps matrix pipe), counted vmcnt(4)
// publish per tile, double-buffered 128KiB LDS, XOR-chunk swizzle.
// W_gate/W_value interleaved at 16-col granularity so silu-combine is
// lane-local in the epilogue.
// Scan: 3-phase chunked, h_t = sigmoid(-g)*h + sigmoid(g)*gfun(hid), f32 carry.

#define DM     1024
#define SEQL   4096
#define FFN    2730
#define FFP    2816
#define NH_OFF 16777216L
#define CHLEN  128

using bf16x8 = __attribute__((ext_vector_type(8))) short;
using f32x4  = __attribute__((ext_vector_type(4))) float;

__device__ __forceinline__ float bf2f(unsigned short h) {
  union { unsigned int u; float f; } v; v.u = ((unsigned int)h) << 16; return v.f;
}
__device__ __forceinline__ unsigned short f2bf(float f) {
  union { float f; unsigned int u; } v; v.f = f;
  unsigned int u = v.u;
  return (unsigned short)((u + 0x7fffu + ((u >> 16) & 1u)) >> 16);
}
__device__ __forceinline__ float ldin(const void* p, long i, int f32mode) {
  return f32mode ? ((const float*)p)[i] : bf2f(((const unsigned short*)p)[i]);
}
__device__ __forceinline__ void stout(void* p, long i, int f32mode, float v) {
  if (f32mode) ((float*)p)[i] = v; else ((unsigned short*)p)[i] = f2bf(v);
}
__device__ __forceinline__ void gload_lds16(const unsigned short* g, unsigned short* lds) {
  __builtin_amdgcn_global_load_lds(
      (const __attribute__((address_space(1))) unsigned int*)g,
      (__attribute__((address_space(3))) unsigned int*)lds,
      16, 0, 0);
}

// ---------------- dtype detection --------------------------------------------
__global__ void detect_k(const unsigned short* __restrict__ x, int* __restrict__ flag) {
  __shared__ int cnt;
  if (threadIdx.x == 0) cnt = 0;
  __syncthreads();
  int c = 0;
  for (int j = 0; j < 4; j++) {
    unsigned short v = x[2 * (threadIdx.x * 4 + j)];
    int ex = (v >> 7) & 0xFF;
    if (ex >= 0x84) c++;
  }
  atomicAdd(&cnt, c);
  __syncthreads();
  if (threadIdx.x == 0) *flag = (cnt >= 32) ? 1 : 0;
}

// ---------------- GEMM: C[M,N] = A[M,K] * B^T  (B stored [N][K], ldb=K) -------
// EPI 0: bf16 plain. EPI 1: bf16 = acc + bias[col] + raw_res (flag).
// EPI 2: bf16 = acc + bf16res. EPI 3: raw_out (flag) = acc + bf16res.
template <int EPI>
__launch_bounds__(256)
__global__ void gemm_bf16(const unsigned short* __restrict__ A, int lda, int aOffZ,
                          const unsigned short* __restrict__ Bm, int bOffZ, int K,
                          void* __restrict__ Cout, int ldc, int cOffZ, long outOff,
                          const unsigned short* __restrict__ bias,
                          const void* __restrict__ res, int ldres, long resOff,
                          const int* __restrict__ flagp) {
  __shared__ __align__(16) unsigned short As[128][64];
  __shared__ __align__(16) unsigned short Bs[128][64];

  const int tid  = threadIdx.x;
  const int w    = tid >> 6;
  const int lane = tid & 63;
  const int z    = blockIdx.z;
  const long tm  = (long)blockIdx.y * 128;
  const long tn  = (long)blockIdx.x * 128;

  const unsigned short* Ag = A + (long)z * aOffZ;
  const unsigned short* Bg = Bm + (long)z * bOffZ;

  f32x4 acc[4][4];
#pragma unroll
  for (int i = 0; i < 4; i++)
#pragma unroll
    for (int j = 0; j < 4; j++) acc[i][j] = (f32x4){0.f, 0.f, 0.f, 0.f};

  const int wrow = w * 32;
  const int srow = lane >> 3;                    // 0..7
  const int scol = (((lane & 7) ^ srow) * 8);    // xor-swizzled source chunk
  const int wm   = (w >> 1) * 64;
  const int wn   = (w & 1) * 64;
  const int quad = lane >> 4;
  const int lo   = lane & 15;
  const int sw   = lo & 7;                       // row-based xor key for reads

  for (int k0 = 0; k0 < K; k0 += 64) {
    __syncthreads();
#pragma unroll
    for (int i = 0; i < 4; i++) {
      const int r = wrow + i * 8;  // wave-uniform LDS base
      gload_lds16(Ag + (tm + r + srow) * (long)lda + k0 + scol, &As[r][0]);
      gload_lds16(Bg + (tn + r + srow) * (long)K + k0 + scol, &Bs[r][0]);
    }
    __syncthreads();
#pragma unroll
    for (int kk = 0; kk < 64; kk += 32) {
      const int kc = kk >> 3;  // 0 or 4
      bf16x8 af[4], bfr[4];
#pragma unroll
      for (int mt = 0; mt < 4; mt++)
        af[mt] = *(const bf16x8*)&As[wm + mt * 16 + lo][((quad + kc) ^ sw) * 8];
#pragma unroll
      for (int nt = 0; nt < 4; nt++)
        bfr[nt] = *(const bf16x8*)&Bs[wn + nt * 16 + lo][((quad + kc) ^ sw) * 8];
#pragma unroll
      for (int mt = 0; mt < 4; mt++)
#pragma unroll
        for (int nt = 0; nt < 4; nt++)
          acc[mt][nt] = __builtin_amdgcn_mfma_f32_16x16x32_bf16(af[mt], bfr[nt], acc[mt][nt], 0, 0, 0);
    }
  }

  const int f32m = (EPI == 1 || EPI == 3) ? *flagp : 0;
#pragma unroll
  for (int mt = 0; mt < 4; mt++) {
#pragma unroll
    for (int nt = 0; nt < 4; nt++) {
#pragma unroll
      for (int r = 0; r < 4; r++) {
        const long grow = tm + wm + mt * 16 + quad * 4 + r;
        const long gcol = tn + wn + nt * 16 + lo;
        float v         = acc[mt][nt][r];
        if (EPI == 0) {
          ((unsigned short*)Cout + (long)z * cOffZ)[grow * (long)ldc + gcol] = f2bf(v);
        } else if (EPI == 1) {
          v += bf2f(bias[gcol]) + ldin(res, resOff + grow * (long)ldres + gcol, f32m);
          ((unsigned short*)Cout)[grow * (long)ldc + gcol] = f2bf(v);
        } else if (EPI == 2) {
          v += bf2f(((const unsigned short*)res + (long)z * cOffZ)[grow * (long)ldres + gcol]);
          ((unsigned short*)Cout + (long)z * cOffZ)[grow * (long)ldc + gcol] = f2bf(v);
        } else {  // EPI == 3: final output
          v += bf2f(((const unsigned short*)res)[grow * (long)ldres + gcol]);
          stout(Cout, outOff + grow * (long)ldc + gcol, f32m, v);
        }
      }
    }
  }
}

// ---------------- fused FF GEMM (legacy 128^2 path, used when MT<256) ---------
__launch_bounds__(256)
__global__ void gemm_ff(const unsigned short* __restrict__ A,
                        const unsigned short* __restrict__ Bgm,
                        const unsigned short* __restrict__ Bvm,
                        unsigned short* __restrict__ Cout) {
  __shared__ __align__(16) unsigned short As[128][64];
  __shared__ __align__(16) unsigned short Bgs[128][64];
  __shared__ __align__(16) unsigned short Bvs[128][64];

  const int tid  = threadIdx.x;
  const int w    = tid >> 6;
  const int lane = tid & 63;
  const long tm  = (long)blockIdx.y * 128;
  const long tn  = (long)blockIdx.x * 128;

  f32x4 accG[4][4], accV[4][4];
#pragma unroll
  for (int i = 0; i < 4; i++)
#pragma unroll
    for (int j = 0; j < 4; j++) {
      accG[i][j] = (f32x4){0.f, 0.f, 0.f, 0.f};
      accV[i][j] = (f32x4){0.f, 0.f, 0.f, 0.f};
    }

  const int wrow = w * 32;
  const int srow = lane >> 3;
  const int scol = (((lane & 7) ^ srow) * 8);
  const int wm   = (w >> 1) * 64;
  const int wn   = (w & 1) * 64;
  const int quad = lane >> 4;
  const int lo   = lane & 15;
  const int sw   = lo & 7;

  for (int k0 = 0; k0 < DM; k0 += 64) {
    __syncthreads();
#pragma unroll
    for (int i = 0; i < 4; i++) {
      const int r = wrow + i * 8;
      gload_lds16(A + (tm + r + srow) * (long)DM + k0 + scol, &As[r][0]);
      gload_lds16(Bgm + (tn + r + srow) * (long)DM + k0 + scol, &Bgs[r][0]);
      gload_lds16(Bvm + (tn + r + srow) * (long)DM + k0 + scol, &Bvs[r][0]);
    }
    __syncthreads();
#pragma unroll
    for (int kk = 0; kk < 64; kk += 32) {
      const int kc = kk >> 3;
      bf16x8 af[4], bfr[4];
#pragma unroll
      for (int mt = 0; mt < 4; mt++)
        af[mt] = *(const bf16x8*)&As[wm + mt * 16 + lo][((quad + kc) ^ sw) * 8];
#pragma unroll
      for (int nt = 0; nt < 4; nt++)
        bfr[nt] = *(const bf16x8*)&Bgs[wn + nt * 16 + lo][((quad + kc) ^ sw) * 8];
#pragma unroll
      for (int mt = 0; mt < 4; mt++)
#pragma unroll
        for (int nt = 0; nt < 4; nt++)
          accG[mt][nt] = __builtin_amdgcn_mfma_f32_16x16x32_bf16(af[mt], bfr[nt], accG[mt][nt], 0, 0, 0);
#pragma unroll
      for (int nt = 0; nt < 4; nt++)
        bfr[nt] = *(const bf16x8*)&Bvs[wn + nt * 16 + lo][((quad + kc) ^ sw) * 8];
#pragma unroll
      for (int mt = 0; mt < 4; mt++)
#pragma unroll
        for (int nt = 0; nt < 4; nt++)
          accV[mt][nt] = __builtin_amdgcn_mfma_f32_16x16x32_bf16(af[mt], bfr[nt], accV[mt][nt], 0, 0, 0);
    }
  }

#pragma unroll
  for (int mt = 0; mt < 4; mt++) {
#pragma unroll
    for (int nt = 0; nt < 4; nt++) {
#pragma unroll
      for (int r = 0; r < 4; r++) {
        const long grow = tm + wm + mt * 16 + quad * 4 + r;
        const long gcol = tn + wn + nt * 16 + lo;
        const float g   = accG[mt][nt][r];
        const float s   = g / (1.f + __expf(-g));
        Cout[grow * (long)FFP + gcol] = f2bf(s * accV[mt][nt][r]);
      }
    }
  }
}

// ---------------- 256^2 pipelined 4-phase GEMM (T2+T3+T4+T5 + reg pipeline) --
// C[M,N'] = A[M,K] * B^T (B stored [NB][K]). 512 threads = 8 waves (2M x 4N).
// Per wave: 128x64 output. BK=64, double-buffered 128 KiB LDS, XOR-chunk
// swizzle. ONE barrier per phase. Register banks aL,aH,b01,b23 form a 1-phase
// software pipeline: phase p's ds_reads (issued AFTER its MFMA cluster) feed
// phase p+1's MFMA, so the LDS pipe overlaps the matrix pipe and the lgkm
// wait at consumption is ~0.
// MFMA quadrants: ph0 aL*b01, ph1 aH*b01, ph2 aL*b23, ph3 aH*b23.
// Reads: ph0 aH(s)<-cb [8]; ph1 b23(s)<-cb [4]; ph2 b01(s+1)<-cb^1 [4];
//        ph3 aL(s+1)<-cb^1 [8].
// Stages (tile s+2 -> cb, into slots whose death barrier has passed and whose
// reads are drained by the phase-start lgkmcnt(0)):
//        ph0 A02 [2]; ph1 A13 [2]; ph2 B0123 [4].
// Publish: vmcnt(4) + barrier at END of ph1 drains all 8 granules of tile s+1
// (in-flight then = {A02,A13}(s+2)); first cross-subtile read of tile s+1 is
// at ph2 — after the publish barrier. Cross-wave visibility = vmcnt-then-bar.
// Tail: subtile NT-2 has no stages -> its ph1 wait is vmcnt(0) (drains tile
// NT-1 fully); subtile NT-1 has no stages/prefetch/wait. NT even, >= 4.
// EPI 0: FF fused. B rows are interleaved gate/value at 16-col granularity
//   (row R: tile=R>>8, pair=(R&255)>>5, sel=(R>>4)&1, col=tile*128+pair*16+(R&15));
//   epilogue: ffin[row][col] = silu(accG)*accV, lane-local (nt even=gate, odd=val).
// EPI 1: out(raw flag) = acc + bf16 res.
template <int EPI>
__launch_bounds__(512, 2)
__global__ void gemm256(const unsigned short* __restrict__ A,
                        const unsigned short* __restrict__ Bm,
                        int K,
                        void* __restrict__ Cout,
                        const unsigned short* __restrict__ res,
                        long outOff,
                        const int* __restrict__ flagp) {
  __shared__ __align__(16) unsigned short As[2][256][64];
  __shared__ __align__(16) unsigned short Bs[2][256][64];

  const int tid  = threadIdx.x;
  const int w    = tid >> 6;
  const int lane = tid & 63;
  const int wr   = w >> 2;      // 0..1
  const int wc   = w & 3;       // 0..3
  const int quad = lane >> 4;
  const int lo   = lane & 15;
  const int sw   = lo & 7;

  // bijective XCD-aware block swizzle (m204 formula)
  const int gx  = gridDim.x;
  int bid       = blockIdx.y * gx + blockIdx.x;
  const int nwg = gx * gridDim.y;
  {
    const int q = nwg >> 3, r8 = nwg & 7;
    const int xc8 = bid & 7, j = bid >> 3;
    bid = (xc8 < r8 ? xc8 * (q + 1) : r8 * (q + 1) + (xc8 - r8) * q) + j;
  }
  const long tn = (long)(bid % gx) * 256;  // B-row tile base
  const long tm = (long)(bid / gx) * 256;  // M tile base

  const int NT = K >> 6;  // even, >= 4 by construction

  // staging source addressing: per-lane swizzled global address, linear LDS
  const int srow = lane >> 3;
  const int sch  = (lane & 7) ^ srow;
  const unsigned short* Ab = A + (tm + (long)w * 8 + srow) * (long)K + sch * 8;
  const unsigned short* Bb = Bm + (tn + (long)w * 8 + srow) * (long)K + sch * 8;

#define STAGE_A(BUF, TT, G) \
  gload_lds16(Ab + (long)((G) * 64) * K + (long)(TT) * 64, &As[BUF][(G) * 64 + w * 8][0])
#define STAGE_B(BUF, TT, G) \
  gload_lds16(Bb + (long)((G) * 64) * K + (long)(TT) * 64, &Bs[BUF][(G) * 64 + w * 8][0])

  // prologue staging, steady-state age order per tile: A02, A13, B0123
  STAGE_A(0, 0, 0); STAGE_A(0, 0, 2);
  STAGE_A(0, 0, 1); STAGE_A(0, 0, 3);
  STAGE_B(0, 0, 0); STAGE_B(0, 0, 1); STAGE_B(0, 0, 2); STAGE_B(0, 0, 3);
  STAGE_A(1, 1, 0); STAGE_A(1, 1, 2);
  STAGE_A(1, 1, 1); STAGE_A(1, 1, 3);
  STAGE_B(1, 1, 0); STAGE_B(1, 1, 1); STAGE_B(1, 1, 2); STAGE_B(1, 1, 3);

  f32x4 acc[8][4];
#pragma unroll
  for (int i = 0; i < 8; i++)
#pragma unroll
    for (int j = 0; j < 4; j++) acc[i][j] = (f32x4){0.f, 0.f, 0.f, 0.f};

  // tile0 landed for every wave: own vmcnt(8) + barrier
  asm volatile("s_waitcnt vmcnt(8)" ::: "memory");
  __builtin_amdgcn_s_barrier();

  bf16x8 aL[4][2], aH[4][2], b01[2][2], b23[2][2];

#define LDAL(CBUF)                                                                \
  _Pragma("unroll") for (int m = 0; m < 4; m++) {                                 \
    _Pragma("unroll") for (int c = 0; c < 2; c++) {                               \
      aL[m][c] = *(const bf16x8*)&As[CBUF][wr * 128 + m * 16 + lo]                \
                                        [((quad + 4 * c) ^ sw) * 8];              \
    }                                                                             \
  }
#define LDAH(CBUF)                                                                \
  _Pragma("unroll") for (int m = 0; m < 4; m++) {                                 \
    _Pragma("unroll") for (int c = 0; c < 2; c++) {                               \
      aH[m][c] = *(const bf16x8*)&As[CBUF][wr * 128 + 64 + m * 16 + lo]           \
                                        [((quad + 4 * c) ^ sw) * 8];              \
    }                                                                             \
  }
#define LDB01(CBUF)                                                               \
  _Pragma("unroll") for (int n = 0; n < 2; n++) {                                 \
    _Pragma("unroll") for (int c = 0; c < 2; c++) {                               \
      b01[n][c] = *(const bf16x8*)&Bs[CBUF][wc * 64 + n * 16 + lo]                \
                                         [((quad + 4 * c) ^ sw) * 8];             \
    }                                                                             \
  }
#define LDB23(CBUF)                                                               \
  _Pragma("unroll") for (int n = 0; n < 2; n++) {                                 \
    _Pragma("unroll") for (int c = 0; c < 2; c++) {                               \
      b23[n][c] = *(const bf16x8*)&Bs[CBUF][wc * 64 + 32 + n * 16 + lo]           \
                                         [((quad + 4 * c) ^ sw) * 8];             \
    }                                                                             \
  }
#define MFMA_Q(MB, AF, NB, BF)                                                    \
  __builtin_amdgcn_s_setprio(1);                                                  \
  _Pragma("unroll") for (int m = 0; m < 4; m++) {                                 \
    _Pragma("unroll") for (int n = 0; n < 2; n++) {                               \
      _Pragma("unroll") for (int c = 0; c < 2; c++) {                             \
        acc[(MB) + m][(NB) + n] = __builtin_amdgcn_mfma_f32_16x16x32_bf16(        \
            AF[m][c], BF[n][c], acc[(MB) + m][(NB) + n], 0, 0, 0);                \
      }                                                                           \
    }                                                                             \
  }                                                                               \
  __builtin_amdgcn_s_setprio(0);

#define LGKM0 asm volatile("s_waitcnt lgkmcnt(0)" ::: "memory")

// One sub-tile. STG: stage tile TT+2; PRF: prefetch reads of tile TT+1;
// VM: 4 = steady publish, 0 = tail full drain, -1 = none.
#define SUBTILE(CBUF, TT, STG, PRF, VM)                                           \
  {                                                                               \
    /* ph0: MFMA aL*b01 */                                                        \
    LGKM0;                                                                        \
    if (STG) { STAGE_A(CBUF, (TT) + 2, 0); STAGE_A(CBUF, (TT) + 2, 2); }          \
    MFMA_Q(0, aL, 0, b01);                                                        \
    LDAH(CBUF);                                                                   \
    __builtin_amdgcn_s_barrier();                                                 \
    /* ph1: MFMA aH*b01 */                                                        \
    LGKM0;                                                                        \
    if (STG) { STAGE_A(CBUF, (TT) + 2, 1); STAGE_A(CBUF, (TT) + 2, 3); }          \
    MFMA_Q(4, aH, 0, b01);                                                        \
    LDB23(CBUF);                                                                  \
    if ((VM) == 4) asm volatile("s_waitcnt vmcnt(4)" ::: "memory");               \
    else if ((VM) == 0) asm volatile("s_waitcnt vmcnt(0)" ::: "memory");          \
    __builtin_amdgcn_s_barrier();                                                 \
    /* ph2: MFMA aL*b23 */                                                        \
    LGKM0;                                                                        \
    if (STG) { STAGE_B(CBUF, (TT) + 2, 0); STAGE_B(CBUF, (TT) + 2, 1);            \
               STAGE_B(CBUF, (TT) + 2, 2); STAGE_B(CBUF, (TT) + 2, 3); }          \
    MFMA_Q(0, aL, 2, b23);                                                        \
    if (PRF) LDB01(CBUF ^ 1);                                                     \
    __builtin_amdgcn_s_barrier();                                                 \
    /* ph3: MFMA aH*b23 (no stages -> no lgkm drain needed) */                    \
    MFMA_Q(4, aH, 2, b23);                                                        \
    if (PRF) LDAL(CBUF ^ 1);                                                      \
    __builtin_amdgcn_s_barrier();                                                 \
  }

  // prologue reads for subtile 0 ph0 (the "ph2/ph3 of subtile -1" prefetch)
  LDB01(0);
  LDAL(0);

  // main loop: s = 0..NT-3 (stages of tile s+2 all valid)
  for (int t = 0; t + 3 < NT; t += 2) {
    SUBTILE(0, t, 1, 1, 4)
    SUBTILE(1, t + 1, 1, 1, 4)
  }
  // tails
  SUBTILE(0, NT - 2, 0, 1, 0)
  SUBTILE(1, NT - 1, 0, 0, -1)

  if (EPI == 0) {
    // silu(gate) * value, lane-local pairing; ffin col base = tn/2
    const long colb = (tn >> 1);
    const long rowb = tm + wr * 128;
#pragma unroll
    for (int m = 0; m < 8; m++) {
#pragma unroll
      for (int np = 0; np < 2; np++) {
        const long col = colb + (wc * 2 + np) * 16 + lo;
#pragma unroll
        for (int r = 0; r < 4; r++) {
          const long row = rowb + m * 16 + quad * 4 + r;
          const float g  = acc[m][2 * np][r];
          const float v  = acc[m][2 * np + 1][r];
          const float s  = g / (1.f + __expf(-g));
          ((unsigned short*)Cout)[row * (long)FFP + col] = f2bf(s * v);
        }
      }
    }
  } else {
    const int f32m = *flagp;
    const long rowb = tm + wr * 128;
    const long colb = tn + wc * 64;
#pragma unroll
    for (int m = 0; m < 8; m++) {
#pragma unroll
      for (int n = 0; n < 4; n++) {
#pragma unroll
        for (int r = 0; r < 4; r++) {
          const long row = rowb + m * 16 + quad * 4 + r;
          const long col = colb + n * 16 + lo;
          float v = acc[m][n][r] + bf2f(res[row * (long)DM + col]);
          stout(Cout, outOff + row * (long)DM + col, f32m, v);
        }
      }
    }
  }
#undef STAGE_A
#undef STAGE_B
#undef LDAL
#undef LDAH
#undef LDB01
#undef LDB23
#undef MFMA_Q
#undef LGKM0
#undef SUBTILE
}

// ---------------- RMSNorm: raw input variant (flag) --------------------------
__global__ void rmsnorm_x(const void* __restrict__ in, long elemOff,
                          const unsigned short* __restrict__ gamma,
                          unsigned short* __restrict__ out,
                          const int* __restrict__ flagp) {
  const int t    = blockIdx.x;
  const int lane = threadIdx.x;
  const int f32m = *flagp;
  float v[16];
  const long base = elemOff + (long)t * DM;
  if (f32m) {
    const float4* rp = (const float4*)((const float*)in + base);
#pragma unroll
    for (int j = 0; j < 4; j++) {
      float4 u     = rp[j * 64 + lane];
      v[j * 4 + 0] = u.x; v[j * 4 + 1] = u.y; v[j * 4 + 2] = u.z; v[j * 4 + 3] = u.w;
    }
  } else {
    const ushort4* rp = (const ushort4*)((const unsigned short*)in + base);
#pragma unroll
    for (int j = 0; j < 4; j++) {
      ushort4 u    = rp[j * 64 + lane];
      v[j * 4 + 0] = bf2f(u.x); v[j * 4 + 1] = bf2f(u.y);
      v[j * 4 + 2] = bf2f(u.z); v[j * 4 + 3] = bf2f(u.w);
    }
  }
  float s = 0.f;
#pragma unroll
  for (int i = 0; i < 16; i++) s = fmaf(v[i], v[i], s);
#pragma unroll
  for (int off = 32; off > 0; off >>= 1) s += __shfl_xor(s, off, 64);
  const float scale = 32.f / fmaxf(sqrtf(s), 1e-12f);
  ushort4* op       = (ushort4*)(out + (long)t * DM);
  const ushort4* gp = (const ushort4*)gamma;
#pragma unroll
  for (int j = 0; j < 4; j++) {
    ushort4 g = gp[j * 64 + lane];
    ushort4 o;
    o.x = f2bf(v[j * 4 + 0] * scale * (bf2f(g.x) + 1.f));
    o.y = f2bf(v[j * 4 + 1] * scale * (bf2f(g.y) + 1.f));
    o.z = f2bf(v[j * 4 + 2] * scale * (bf2f(g.z) + 1.f));
    o.w = f2bf(v[j * 4 + 3] * scale * (bf2f(g.w) + 1.f));
    op[j * 64 + lane] = o;
  }
}

// ---------------- RMSNorm (bf16 in/out) --------------------------------------
__global__ void rmsnorm_k(const unsigned short* __restrict__ in,
                          const unsigned short* __restrict__ gamma,
                          unsigned short* __restrict__ out) {
  const int t    = blockIdx.x;
  const int lane = threadIdx.x;
  float v[16];
  const ushort4* rp = (const ushort4*)(in + (long)t * DM);
#pragma unroll
  for (int j = 0; j < 4; j++) {
    ushort4 u    = rp[j * 64 + lane];
    v[j * 4 + 0] = bf2f(u.x); v[j * 4 + 1] = bf2f(u.y);
    v[j * 4 + 2] = bf2f(u.z); v[j * 4 + 3] = bf2f(u.w);
  }
  float s = 0.f;
#pragma unroll
  for (int i = 0; i < 16; i++) s = fmaf(v[i], v[i], s);
#pragma unroll
  for (int off = 32; off > 0; off >>= 1) s += __shfl_xor(s, off, 64);
  const float scale = 32.f / fmaxf(sqrtf(s), 1e-12f);
  ushort4* op       = (ushort4*)(out + (long)t * DM);
  const ushort4* gp = (const ushort4*)gamma;
#pragma unroll
  for (int j = 0; j < 4; j++) {
    ushort4 g = gp[j * 64 + lane];
    ushort4 o;
    o.x = f2bf(v[j * 4 + 0] * scale * (bf2f(g.x) + 1.f));
    o.y = f2bf(v[j * 4 + 1] * scale * (bf2f(g.y) + 1.f));
    o.z = f2bf(v[j * 4 + 2] * scale * (bf2f(g.z) + 1.f));
    o.w = f2bf(v[j * 4 + 3] * scale * (bf2f(g.w) + 1.f));
    op[j * 64 + lane] = o;
  }
}

// ---------------- causal depthwise conv K=4 ----------------------------------
__global__ void dwconv_k(const unsigned short* __restrict__ xn,
                         const unsigned short* __restrict__ dww,
                         const unsigned short* __restrict__ dwb,
                         unsigned short* __restrict__ y, int l0) {
  const int t = blockIdx.x;
  const int d = blockIdx.y * 256 + threadIdx.x;
  const int l = l0 + (t & (SEQL - 1));
  ushort4 w4  = ((const ushort4*)dww)[d];
  float wk[4] = {bf2f(w4.x), bf2f(w4.y), bf2f(w4.z), bf2f(w4.w)};
  float acc   = bf2f(dwb[d]);
#pragma unroll
  for (int k = 0; k < 4; k++) {
    const int ll = l + k - 3;
    if (ll >= 0) acc = fmaf(bf2f(xn[(long)(t + k - 3) * DM + d]), wk[k], acc);
  }
  y[(long)t * DM + d] = f2bf(acc);
}

// ---------------- scan --------------------------------------------------------
__device__ __forceinline__ void cv_compute(float gt, float& c, float& sg) {
  gt = fminf(fmaxf(gt, -40.f), 40.f);
  const float e  = __expf(-fabsf(gt));
  const float r  = 1.f / (1.f + e);
  const float rs = e * r;
  c  = (gt >= 0.f) ? rs : r;   // sigmoid(-gt)
  sg = (gt >= 0.f) ? r : rs;   // sigmoid(gt)
}
__device__ __forceinline__ float gfun(float hid) {
  hid = fminf(fmaxf(hid, -40.f), 40.f);
  if (hid >= 0.f) return hid + 0.5f;
  const float e = __expf(hid);
  return e / (1.f + e);
}

__global__ void scan_p1(const unsigned short* __restrict__ hg, float* __restrict__ cC,
                        float* __restrict__ cV, int chTot, int SL) {
  const int e = threadIdx.x, bh = blockIdx.y, cid = blockIdx.x;
  const int bL = bh >> 2, hh = bh & 3;
  long base = ((long)(bL * SL + cid * CHLEN)) * 3072 + hh * 768 + e;
  float C = 1.f, V = 0.f;
  for (int i = 0; i < CHLEN; i++) {
    const float hid = bf2f(hg[base]), gt = bf2f(hg[base + 384]);
    float c, sg; cv_compute(gt, c, sg);
    C *= c;
    V = fmaf(c, V, sg * gfun(hid));
    base += 3072;
  }
  const int idx = cid * chTot + bh * 384 + e;
  cC[idx] = C; cV[idx] = V;
}

__global__ void scan_p2(const float* __restrict__ cC, const float* __restrict__ cV,
                        float* __restrict__ hin, int chTot, int CHNp,
                        const float* __restrict__ hcarry, int useCarry) {
  const int ch = blockIdx.x * 384 + threadIdx.x;
  float h = useCarry ? hcarry[ch] : 0.f;
  for (int cid = 0; cid < CHNp; cid++) {
    const int idx = cid * chTot + ch;
    hin[idx] = h;
    h = fmaf(cC[idx], h, cV[idx]);
  }
}

__global__ void scan_p3(const unsigned short* __restrict__ hg, const float* __restrict__ hin,
                        unsigned short* __restrict__ hout, void* __restrict__ nh, long nhOff,
                        float* __restrict__ hcarry, int chTot, int SL, int CHNp,
                        int writeNh, const int* __restrict__ flagp) {
  const int e = threadIdx.x, bh = blockIdx.y, cid = blockIdx.x;
  const int bL = bh >> 2, hh = bh & 3;
  const long tok = (long)bL * SL + (long)cid * CHLEN;
  long base  = tok * 3072 + hh * 768 + e;
  long obase = tok * 1536 + hh * 384 + e;
  float h = hin[cid * chTot + bh * 384 + e];
  for (int i = 0; i < CHLEN; i++) {
    const float hid = bf2f(hg[base]), gt = bf2f(hg[base + 384]);
    float c, sg; cv_compute(gt, c, sg);
    h = fmaf(c, h, sg * gfun(hid));
    hout[obase] = f2bf(h);
    base += 3072; obase += 1536;
  }
  if (cid == CHNp - 1) {
    hcarry[bh * 384 + e] = h;
    if (writeNh) stout(nh, nhOff + bL * 1536 + hh * 384 + e, *flagp, h);
  }
}

// ---------------- weight conversion / transposes (flag-branching reads) -------
__global__ void cvt_k(const void* __restrict__ in, unsigned short* __restrict__ out,
                      int n, const int* __restrict__ flagp) {
  const int i = blockIdx.x * 256 + threadIdx.x;
  if (i < n) out[i] = f2bf(ldin(in, i, *flagp));
}
__global__ void tr_whg(const void* __restrict__ in, unsigned short* __restrict__ out,
                       const int* __restrict__ flagp) {
  const int idx = blockIdx.x * 256 + threadIdx.x;  // (h*768+n)*256+k
  const int k = idx & 255, n = (idx >> 8) % 768, h = idx / (768 * 256);
  out[idx] = f2bf(ldin(in, (long)(h * 256 + k) * 768 + n, *flagp));
}
__global__ void tr_wout(const void* __restrict__ in, unsigned short* __restrict__ out,
                        const int* __restrict__ flagp) {
  const int idx = blockIdx.x * 256 + threadIdx.x;  // (h*256+n)*384+k
  const int k = idx % 384, n = (idx / 384) & 255, h = idx / (384 * 256);
  out[idx] = f2bf(ldin(in, (long)(h * 384 + k) * 256 + n, *flagp));
}
__global__ void tr_wg(const void* __restrict__ in, unsigned short* __restrict__ out,
                      const int* __restrict__ flagp) {
  const int idx = blockIdx.x * 256 + threadIdx.x;  // n*1024+k, n<2816
  const int k = idx & 1023, n = idx >> 10;
  out[idx] = (n < FFN) ? f2bf(ldin(in, (long)k * FFN + n, *flagp)) : (unsigned short)0;
}
// interleaved gate/value: B row R -> tile=R>>8, pair=(R&255)>>5, sel=(R>>4)&1,
// col = tile*128 + pair*16 + (R&15); out[R][k] = W_{sel}[k][col] (0 if col>=FFN)
__global__ void tr_wgv(const void* __restrict__ wg, const void* __restrict__ wv,
                       unsigned short* __restrict__ out, const int* __restrict__ flagp) {
  const int idx = blockIdx.x * 256 + threadIdx.x;  // R*1024+k, R<5632
  const int k = idx & 1023, R = idx >> 10;
  const int tile = R >> 8, rb = R & 255;
  const int pair = rb >> 5, sel = (rb >> 4) & 1, r16 = rb & 15;
  const int col  = tile * 128 + pair * 16 + r16;
  const void* src = sel ? wv : wg;
  out[idx] = (col < FFN) ? f2bf(ldin(src, (long)k * FFN + col, *flagp)) : (unsigned short)0;
}
__global__ void tr_wfo(const void* __restrict__ in, unsigned short* __restrict__ out,
                       const int* __restrict__ flagp) {
  const int idx = blockIdx.x * 256 + threadIdx.x;  // n*2816+kk
  const int kk = idx % FFP, n = idx / FFP;
  out[idx] = (kk < FFN) ? f2bf(ldin(in, (long)kk * DM + n, *flagp)) : (unsigned short)0;
}

// ---------------- launch ------------------------------------------------------
extern "C" void kernel_launch(void* const* d_in, const int* in_sizes, int n_in,
                              void* d_out, int out_size, void* d_ws, size_t ws_size,
                              hipStream_t stream) {
  const void* x      = d_in[0];
  const void* dw_w   = d_in[1];
  const void* dw_b   = d_in[2];
  const void* pw_w   = d_in[3];  // [N=1024][K=1024] already
  const void* pw_b   = d_in[4];
  const void* conv_g = d_in[5];
  const void* gru_g  = d_in[6];
  const void* ff_g   = d_in[7];
  const void* w_hg   = d_in[8];
  const void* w_out  = d_in[9];
  const void* w_gate = d_in[10];
  const void* w_val  = d_in[11];
  const void* w_ffo  = d_in[12];

  // Pass size from ws_size (deterministic): need(MT) = 21,795,072 + MT*13,888.
  const long FIXED = 21795072L;
  int MT = 128;
  if      (ws_size >= (size_t)(FIXED + 16384L * 13888)) MT = 16384;
  else if (ws_size >= (size_t)(FIXED + 8192L * 13888))  MT = 8192;
  else if (ws_size >= (size_t)(FIXED + 4096L * 13888))  MT = 4096;
  else if (ws_size >= (size_t)(FIXED + 2048L * 13888))  MT = 2048;
  else if (ws_size >= (size_t)(FIXED + 1024L * 13888))  MT = 1024;
  else if (ws_size >= (size_t)(FIXED + 512L * 13888))   MT = 512;
  else if (ws_size >= (size_t)(FIXED + 256L * 13888))   MT = 256;

  const int SL    = (MT >= SEQL) ? SEQL : MT;
  const int nSeq  = MT / SL;
  const int CHNp  = SL / CHLEN;
  const int chTot = nSeq * 1536;
  const int big   = (MT >= 256);  // 256^2 pipelined path for the two FF GEMMs

  char* p = (char*)d_ws;
  unsigned short* whgT  = (unsigned short*)p; p += 1572864;
  unsigned short* woutT = (unsigned short*)p; p += 786432;
  unsigned short* wgT   = (unsigned short*)p; p += 5767168;
  unsigned short* wvT   = (unsigned short*)p; p += 5767168;
  unsigned short* wfoT  = (unsigned short*)p; p += 5767168;
  unsigned short* pwT   = (unsigned short*)p; p += 2097152;
  unsigned short* dwwB  = (unsigned short*)p; p += 8192;
  unsigned short* dwbB  = (unsigned short*)p; p += 2048;
  unsigned short* pwbB  = (unsigned short*)p; p += 2048;
  unsigned short* cgB   = (unsigned short*)p; p += 2048;
  unsigned short* ggB   = (unsigned short*)p; p += 2048;
  unsigned short* fgB   = (unsigned short*)p; p += 2048;
  int*            flag  = (int*)p;            p += 256;
  float*          hcarry= (float*)p;          p += 12288;
  float*          cC    = (float*)p;          p += (long)MT * 192;
  float*          cV    = (float*)p;          p += (long)MT * 192;
  float*          hin   = (float*)p;          p += (long)MT * 192;
  unsigned short* xnb   = (unsigned short*)p; p += 6144 + (long)MT * 2048;
  unsigned short* xc    = (unsigned short*)p; p += (long)MT * 2048;
  unsigned short* hbuf  = (unsigned short*)p; p += (long)MT * 3072;
  unsigned short* ybuf  = (unsigned short*)p;  // region R: ybuf / hg / ffin
  unsigned short* hg    = (unsigned short*)p;
  unsigned short* ffin  = (unsigned short*)p;
  unsigned short* xn    = xnb + 3 * DM;
  unsigned short* wgvT  = wgT;  // interleaved [5632][1024] spans wgT+wvT slots

  // dtype detection + weight conversion (once per call)
  detect_k<<<1, 256, 0, stream>>>((const unsigned short*)x, flag);
  tr_whg<<<3072, 256, 0, stream>>>(w_hg, whgT, flag);
  tr_wout<<<1536, 256, 0, stream>>>(w_out, woutT, flag);
  if (big) {
    tr_wgv<<<22528, 256, 0, stream>>>(w_gate, w_val, wgvT, flag);
  } else {
    tr_wg<<<11264, 256, 0, stream>>>(w_gate, wgT, flag);
    tr_wg<<<11264, 256, 0, stream>>>(w_val, wvT, flag);
  }
  tr_wfo<<<11264, 256, 0, stream>>>(w_ffo, wfoT, flag);
  cvt_k<<<4096, 256, 0, stream>>>(pw_w, pwT, 1048576, flag);
  cvt_k<<<16, 256, 0, stream>>>(dw_w, dwwB, 4096, flag);
  cvt_k<<<4, 256, 0, stream>>>(dw_b, dwbB, 1024, flag);
  cvt_k<<<4, 256, 0, stream>>>(pw_b, pwbB, 1024, flag);
  cvt_k<<<4, 256, 0, stream>>>(conv_g, cgB, 1024, flag);
  cvt_k<<<4, 256, 0, stream>>>(gru_g, ggB, 1024, flag);
  cvt_k<<<4, 256, 0, stream>>>(ff_g, fgB, 1024, flag);

  for (long t0 = 0; t0 < 16384; t0 += MT) {
    const int l0     = (int)(t0 & (SEQL - 1));
    const int P      = (l0 > 0) ? 3 : 0;
    const int seqEnd = (l0 + SL == SEQL);
    const long nhOff = NH_OFF + (t0 / SEQL) * 1536;

    // conv block: xc = pw(dwconv(rmsnorm(x))) + pw_b + x
    rmsnorm_x<<<MT + P, 64, 0, stream>>>(x, (t0 - P) * DM, cgB, xn - (long)P * DM, flag);
    dwconv_k<<<dim3(MT, 4), 256, 0, stream>>>(xn, dwwB, dwbB, ybuf, l0);
    gemm_bf16<1><<<dim3(8, MT / 128, 1), 256, 0, stream>>>(ybuf, DM, 0, pwT, 0, DM,
        xc, DM, 0, 0L, pwbB, x, DM, t0 * DM, flag);

    // GRU block
    rmsnorm_k<<<MT, 64, 0, stream>>>(xc, ggB, xn);
    gemm_bf16<0><<<dim3(6, MT / 128, 4), 256, 0, stream>>>(xn, DM, 256, whgT, 196608, 256,
        hg, 3072, 768, 0L, nullptr, nullptr, 0, 0L, nullptr);
    scan_p1<<<dim3(CHNp, nSeq * 4), 384, 0, stream>>>(hg, cC, cV, chTot, SL);
    scan_p2<<<nSeq * 4, 384, 0, stream>>>(cC, cV, hin, chTot, CHNp, hcarry, l0 > 0);
    scan_p3<<<dim3(CHNp, nSeq * 4), 384, 0, stream>>>(hg, hin, hbuf, d_out, nhOff,
        hcarry, chTot, SL, CHNp, seqEnd, flag);
    gemm_bf16<2><<<dim3(2, MT / 128, 4), 256, 0, stream>>>(hbuf, 1536, 384, woutT, 98304, 384,
        xc, DM, 256, 0L, nullptr, xc, DM, 0L, nullptr);

    // FF block
    rmsnorm_k<<<MT, 64, 0, stream>>>(xc, fgB, xn);
    if (big) {
      gemm256<0><<<dim3(22, MT / 256), 512, 0, stream>>>(xn, wgvT, DM,
          ffin, nullptr, 0L, nullptr);
      gemm256<1><<<dim3(4, MT / 256), 512, 0, stream>>>(ffin, wfoT, FFP,
          d_out, xc, t0 * DM, flag);
    } else {
      gemm_ff<<<dim3(22, MT / 128), 256, 0, stream>>>(xn, wgT, wvT, ffin);
      gemm_bf16<3><<<dim3(8, MT / 128, 1), 256, 0, stream>>>(ffin, FFP, 0, wfoT, 0, FFP,
          d_out, DM, 0, t0 * DM, nullptr, xc, DM, 0L, flag);
    }
  }
}

// Round 5
// 966.442 us; speedup vs baseline: 1.0995x; 1.0995x over previous
//
#include <hip/hip_runtime.h>
#include <stdint.h>

// MinGRUBlock on MI355X (gfx950). Input/output dtype (f32 vs bf16) DETECTED at
// runtime from x's bit patterns (flag in ws). Internals bf16. Residual in ws.
// Small GEMMs: mfma_f32_16x16x32_bf16, 128x128 tile, BK=64, global_load_lds
// w=16, XOR-swizzled LDS (chunk c of row r at c^(r&7)).
// Big GEMMs (FF gate/value and FF out): 256x256 tile, 8 waves, 4-phase-per-tile
// schedule, ONE barrier per phase, REGISTER-LIGHT pipeline (quadrant order
// L*b01, L*b23, H*b23, H*b01 so each operand bank serves 2 phases from regs;
// peak live fragments = 64 VGPR, acc = 128 AGPR -> fits the 256-reg budget at
// 2 waves/SIMD with NO spill), counted vmcnt(8), dbuf 128KiB LDS, XOR swizzle.
// W_gate/W_value interleaved at 16-col granularity so silu-combine is
// lane-local in the epilogue.
// Scan: 3-phase chunked, h_t = sigmoid(-g)*h + sigmoid(g)*gfun(hid), f32 carry.

#define DM     1024
#define SEQL   4096
#define FFN    2730
#define FFP    2816
#define NH_OFF 16777216L
#define CHLEN  128

using bf16x8 = __attribute__((ext_vector_type(8))) short;
using f32x4  = __attribute__((ext_vector_type(4))) float;

__device__ __forceinline__ float bf2f(unsigned short h) {
  union { unsigned int u; float f; } v; v.u = ((unsigned int)h) << 16; return v.f;
}
__device__ __forceinline__ unsigned short f2bf(float f) {
  union { float f; unsigned int u; } v; v.f = f;
  unsigned int u = v.u;
  return (unsigned short)((u + 0x7fffu + ((u >> 16) & 1u)) >> 16);
}
__device__ __forceinline__ float ldin(const void* p, long i, int f32mode) {
  return f32mode ? ((const float*)p)[i] : bf2f(((const unsigned short*)p)[i]);
}
__device__ __forceinline__ void stout(void* p, long i, int f32mode, float v) {
  if (f32mode) ((float*)p)[i] = v; else ((unsigned short*)p)[i] = f2bf(v);
}
__device__ __forceinline__ void gload_lds16(const unsigned short* g, unsigned short* lds) {
  __builtin_amdgcn_global_load_lds(
      (const __attribute__((address_space(1))) unsigned int*)g,
      (__attribute__((address_space(3))) unsigned int*)lds,
      16, 0, 0);
}

// ---------------- dtype detection --------------------------------------------
__global__ void detect_k(const unsigned short* __restrict__ x, int* __restrict__ flag) {
  __shared__ int cnt;
  if (threadIdx.x == 0) cnt = 0;
  __syncthreads();
  int c = 0;
  for (int j = 0; j < 4; j++) {
    unsigned short v = x[2 * (threadIdx.x * 4 + j)];
    int ex = (v >> 7) & 0xFF;
    if (ex >= 0x84) c++;
  }
  atomicAdd(&cnt, c);
  __syncthreads();
  if (threadIdx.x == 0) *flag = (cnt >= 32) ? 1 : 0;
}

// ---------------- GEMM: C[M,N] = A[M,K] * B^T  (B stored [N][K], ldb=K) -------
// EPI 0: bf16 plain. EPI 1: bf16 = acc + bias[col] + raw_res (flag).
// EPI 2: bf16 = acc + bf16res. EPI 3: raw_out (flag) = acc + bf16res.
template <int EPI>
__launch_bounds__(256)
__global__ void gemm_bf16(const unsigned short* __restrict__ A, int lda, int aOffZ,
                          const unsigned short* __restrict__ Bm, int bOffZ, int K,
                          void* __restrict__ Cout, int ldc, int cOffZ, long outOff,
                          const unsigned short* __restrict__ bias,
                          const void* __restrict__ res, int ldres, long resOff,
                          const int* __restrict__ flagp) {
  __shared__ __align__(16) unsigned short As[128][64];
  __shared__ __align__(16) unsigned short Bs[128][64];

  const int tid  = threadIdx.x;
  const int w    = tid >> 6;
  const int lane = tid & 63;
  const int z    = blockIdx.z;
  const long tm  = (long)blockIdx.y * 128;
  const long tn  = (long)blockIdx.x * 128;

  const unsigned short* Ag = A + (long)z * aOffZ;
  const unsigned short* Bg = Bm + (long)z * bOffZ;

  f32x4 acc[4][4];
#pragma unroll
  for (int i = 0; i < 4; i++)
#pragma unroll
    for (int j = 0; j < 4; j++) acc[i][j] = (f32x4){0.f, 0.f, 0.f, 0.f};

  const int wrow = w * 32;
  const int srow = lane >> 3;                    // 0..7
  const int scol = (((lane & 7) ^ srow) * 8);    // xor-swizzled source chunk
  const int wm   = (w >> 1) * 64;
  const int wn   = (w & 1) * 64;
  const int quad = lane >> 4;
  const int lo   = lane & 15;
  const int sw   = lo & 7;                       // row-based xor key for reads

  for (int k0 = 0; k0 < K; k0 += 64) {
    __syncthreads();
#pragma unroll
    for (int i = 0; i < 4; i++) {
      const int r = wrow + i * 8;  // wave-uniform LDS base
      gload_lds16(Ag + (tm + r + srow) * (long)lda + k0 + scol, &As[r][0]);
      gload_lds16(Bg + (tn + r + srow) * (long)K + k0 + scol, &Bs[r][0]);
    }
    __syncthreads();
#pragma unroll
    for (int kk = 0; kk < 64; kk += 32) {
      const int kc = kk >> 3;  // 0 or 4
      bf16x8 af[4], bfr[4];
#pragma unroll
      for (int mt = 0; mt < 4; mt++)
        af[mt] = *(const bf16x8*)&As[wm + mt * 16 + lo][((quad + kc) ^ sw) * 8];
#pragma unroll
      for (int nt = 0; nt < 4; nt++)
        bfr[nt] = *(const bf16x8*)&Bs[wn + nt * 16 + lo][((quad + kc) ^ sw) * 8];
#pragma unroll
      for (int mt = 0; mt < 4; mt++)
#pragma unroll
        for (int nt = 0; nt < 4; nt++)
          acc[mt][nt] = __builtin_amdgcn_mfma_f32_16x16x32_bf16(af[mt], bfr[nt], acc[mt][nt], 0, 0, 0);
    }
  }

  const int f32m = (EPI == 1 || EPI == 3) ? *flagp : 0;
#pragma unroll
  for (int mt = 0; mt < 4; mt++) {
#pragma unroll
    for (int nt = 0; nt < 4; nt++) {
#pragma unroll
      for (int r = 0; r < 4; r++) {
        const long grow = tm + wm + mt * 16 + quad * 4 + r;
        const long gcol = tn + wn + nt * 16 + lo;
        float v         = acc[mt][nt][r];
        if (EPI == 0) {
          ((unsigned short*)Cout + (long)z * cOffZ)[grow * (long)ldc + gcol] = f2bf(v);
        } else if (EPI == 1) {
          v += bf2f(bias[gcol]) + ldin(res, resOff + grow * (long)ldres + gcol, f32m);
          ((unsigned short*)Cout)[grow * (long)ldc + gcol] = f2bf(v);
        } else if (EPI == 2) {
          v += bf2f(((const unsigned short*)res + (long)z * cOffZ)[grow * (long)ldres + gcol]);
          ((unsigned short*)Cout + (long)z * cOffZ)[grow * (long)ldc + gcol] = f2bf(v);
        } else {  // EPI == 3: final output
          v += bf2f(((const unsigned short*)res)[grow * (long)ldres + gcol]);
          stout(Cout, outOff + grow * (long)ldc + gcol, f32m, v);
        }
      }
    }
  }
}

// ---------------- fused FF GEMM (legacy 128^2 path, used when MT<256) ---------
__launch_bounds__(256)
__global__ void gemm_ff(const unsigned short* __restrict__ A,
                        const unsigned short* __restrict__ Bgm,
                        const unsigned short* __restrict__ Bvm,
                        unsigned short* __restrict__ Cout) {
  __shared__ __align__(16) unsigned short As[128][64];
  __shared__ __align__(16) unsigned short Bgs[128][64];
  __shared__ __align__(16) unsigned short Bvs[128][64];

  const int tid  = threadIdx.x;
  const int w    = tid >> 6;
  const int lane = tid & 63;
  const long tm  = (long)blockIdx.y * 128;
  const long tn  = (long)blockIdx.x * 128;

  f32x4 accG[4][4], accV[4][4];
#pragma unroll
  for (int i = 0; i < 4; i++)
#pragma unroll
    for (int j = 0; j < 4; j++) {
      accG[i][j] = (f32x4){0.f, 0.f, 0.f, 0.f};
      accV[i][j] = (f32x4){0.f, 0.f, 0.f, 0.f};
    }

  const int wrow = w * 32;
  const int srow = lane >> 3;
  const int scol = (((lane & 7) ^ srow) * 8);
  const int wm   = (w >> 1) * 64;
  const int wn   = (w & 1) * 64;
  const int quad = lane >> 4;
  const int lo   = lane & 15;
  const int sw   = lo & 7;

  for (int k0 = 0; k0 < DM; k0 += 64) {
    __syncthreads();
#pragma unroll
    for (int i = 0; i < 4; i++) {
      const int r = wrow + i * 8;
      gload_lds16(A + (tm + r + srow) * (long)DM + k0 + scol, &As[r][0]);
      gload_lds16(Bgm + (tn + r + srow) * (long)DM + k0 + scol, &Bgs[r][0]);
      gload_lds16(Bvm + (tn + r + srow) * (long)DM + k0 + scol, &Bvs[r][0]);
    }
    __syncthreads();
#pragma unroll
    for (int kk = 0; kk < 64; kk += 32) {
      const int kc = kk >> 3;
      bf16x8 af[4], bfr[4];
#pragma unroll
      for (int mt = 0; mt < 4; mt++)
        af[mt] = *(const bf16x8*)&As[wm + mt * 16 + lo][((quad + kc) ^ sw) * 8];
#pragma unroll
      for (int nt = 0; nt < 4; nt++)
        bfr[nt] = *(const bf16x8*)&Bgs[wn + nt * 16 + lo][((quad + kc) ^ sw) * 8];
#pragma unroll
      for (int mt = 0; mt < 4; mt++)
#pragma unroll
        for (int nt = 0; nt < 4; nt++)
          accG[mt][nt] = __builtin_amdgcn_mfma_f32_16x16x32_bf16(af[mt], bfr[nt], accG[mt][nt], 0, 0, 0);
#pragma unroll
      for (int nt = 0; nt < 4; nt++)
        bfr[nt] = *(const bf16x8*)&Bvs[wn + nt * 16 + lo][((quad + kc) ^ sw) * 8];
#pragma unroll
      for (int mt = 0; mt < 4; mt++)
#pragma unroll
        for (int nt = 0; nt < 4; nt++)
          accV[mt][nt] = __builtin_amdgcn_mfma_f32_16x16x32_bf16(af[mt], bfr[nt], accV[mt][nt], 0, 0, 0);
    }
  }

#pragma unroll
  for (int mt = 0; mt < 4; mt++) {
#pragma unroll
    for (int nt = 0; nt < 4; nt++) {
#pragma unroll
      for (int r = 0; r < 4; r++) {
        const long grow = tm + wm + mt * 16 + quad * 4 + r;
        const long gcol = tn + wn + nt * 16 + lo;
        const float g   = accG[mt][nt][r];
        const float s   = g / (1.f + __expf(-g));
        Cout[grow * (long)FFP + gcol] = f2bf(s * accV[mt][nt][r]);
      }
    }
  }
}

// ---------------- 256^2 4-phase GEMM, register-light pipeline ----------------
// C[M,N'] = A[M,K] * B^T (B stored [NB][K]). 512 threads = 8 waves (2M x 4N).
// Per wave: 128x64 output. BK=64, double-buffered 128 KiB LDS, XOR-chunk
// swizzle, ONE barrier per phase. Quadrant order reuses operand banks across
// adjacent phases so only 2 of 4 phases have in-phase LDS read waits and peak
// live fragments = 64 VGPR (aL32/b01 16/b23 16 at P0; aH32/b23 16/b01 16 at
// P2). acc = 128 AGPR; total fits 256-reg budget at 2 waves/SIMD, NO spill
// (round-3 spill: WRITE_SIZE 90->244 MB — the check for this design).
// Phases (tile s, buf cb=s&1, compile-time via 2x unroll):
//   P0: read aL,b01 (in-phase); MFMA aL*b01; prefetch b23;        bar
//   P1: MFMA aL*b23 (all regs);                                   bar
//   P2: stage B(s+2)->cb; read aH (in-phase); MFMA aH*b23;        bar
//   P3: stage A(s+2)->cb; MFMA aH*b01 (all regs); vmcnt(8);       bar
// Deaths: b01 drained@P0-MFMA, b23@P1-MFMA -> B slots dead after P1 bar ->
// stage B @P2. aL@P0/P1, aH@P2 drained pre-P2-bar -> A slots dead -> stage A
// @P3. Publish: vmcnt(8) leaves exactly {B(s+2),A(s+2)} in flight and drains
// tile s+1 (issued @P2/P3 of s-1) before P0(s+1) reads it. Cross-wave
// visibility = vmcnt-then-barrier. Tail: s=NT-2 no stages, vmcnt(0);
// s=NT-1 no stages, no wait. NT even, >= 4 (K=1024 -> 16, K=2816 -> 44).
// EPI 0: FF fused. B rows are interleaved gate/value at 16-col granularity
//   (row R: tile=R>>8, pair=(R&255)>>5, sel=(R>>4)&1, col=tile*128+pair*16+(R&15));
//   epilogue: ffin[row][col] = silu(accG)*accV, lane-local (nt even=gate, odd=val).
// EPI 1: out(raw flag) = acc + bf16 res.
template <int EPI>
__launch_bounds__(512, 2)
__global__ void gemm256(const unsigned short* __restrict__ A,
                        const unsigned short* __restrict__ Bm,
                        int K,
                        void* __restrict__ Cout,
                        const unsigned short* __restrict__ res,
                        long outOff,
                        const int* __restrict__ flagp) {
  __shared__ __align__(16) unsigned short As[2][256][64];
  __shared__ __align__(16) unsigned short Bs[2][256][64];

  const int tid  = threadIdx.x;
  const int w    = tid >> 6;
  const int lane = tid & 63;
  const int wr   = w >> 2;      // 0..1
  const int wc   = w & 3;       // 0..3
  const int quad = lane >> 4;
  const int lo   = lane & 15;
  const int sw   = lo & 7;

  // bijective XCD-aware block swizzle (m204 formula)
  const int gx  = gridDim.x;
  int bid       = blockIdx.y * gx + blockIdx.x;
  const int nwg = gx * gridDim.y;
  {
    const int q = nwg >> 3, r8 = nwg & 7;
    const int xc8 = bid & 7, j = bid >> 3;
    bid = (xc8 < r8 ? xc8 * (q + 1) : r8 * (q + 1) + (xc8 - r8) * q) + j;
  }
  const long tn = (long)(bid % gx) * 256;  // B-row tile base
  const long tm = (long)(bid / gx) * 256;  // M tile base

  const int NT = K >> 6;  // even, >= 4 by construction

  // staging source addressing: per-lane swizzled global address, linear LDS
  const int srow = lane >> 3;
  const int sch  = (lane & 7) ^ srow;
  const unsigned short* Ab = A + (tm + (long)w * 8 + srow) * (long)K + sch * 8;
  const unsigned short* Bb = Bm + (tn + (long)w * 8 + srow) * (long)K + sch * 8;

#define STAGE_A(BUF, TT, G) \
  gload_lds16(Ab + (long)((G) * 64) * K + (long)(TT) * 64, &As[BUF][(G) * 64 + w * 8][0])
#define STAGE_B(BUF, TT, G) \
  gload_lds16(Bb + (long)((G) * 64) * K + (long)(TT) * 64, &Bs[BUF][(G) * 64 + w * 8][0])

  // prologue staging in steady-state age order: A0,B0 (tile0), B1,A1 (tile1)
  STAGE_A(0, 0, 0); STAGE_A(0, 0, 1); STAGE_A(0, 0, 2); STAGE_A(0, 0, 3);
  STAGE_B(0, 0, 0); STAGE_B(0, 0, 1); STAGE_B(0, 0, 2); STAGE_B(0, 0, 3);
  STAGE_B(1, 1, 0); STAGE_B(1, 1, 1); STAGE_B(1, 1, 2); STAGE_B(1, 1, 3);
  STAGE_A(1, 1, 0); STAGE_A(1, 1, 1); STAGE_A(1, 1, 2); STAGE_A(1, 1, 3);

  f32x4 acc[8][4];
#pragma unroll
  for (int i = 0; i < 8; i++)
#pragma unroll
    for (int j = 0; j < 4; j++) acc[i][j] = (f32x4){0.f, 0.f, 0.f, 0.f};

  // tile0 landed for every wave (tile1's 8 remain in flight)
  asm volatile("s_waitcnt vmcnt(8)" ::: "memory");
  __builtin_amdgcn_s_barrier();

  bf16x8 aL[4][2], aH[4][2], b01[2][2], b23[2][2];

#define LDAL(CBUF)                                                                \
  _Pragma("unroll") for (int m = 0; m < 4; m++) {                                 \
    _Pragma("unroll") for (int c = 0; c < 2; c++) {                               \
      aL[m][c] = *(const bf16x8*)&As[CBUF][wr * 128 + m * 16 + lo]                \
                                        [((quad + 4 * c) ^ sw) * 8];              \
    }                                                                             \
  }
#define LDAH(CBUF)                                                                \
  _Pragma("unroll") for (int m = 0; m < 4; m++) {                                 \
    _Pragma("unroll") for (int c = 0; c < 2; c++) {                               \
      aH[m][c] = *(const bf16x8*)&As[CBUF][wr * 128 + 64 + m * 16 + lo]           \
                                        [((quad + 4 * c) ^ sw) * 8];              \
    }                                                                             \
  }
#define LDB01(CBUF)                                                               \
  _Pragma("unroll") for (int n = 0; n < 2; n++) {                                 \
    _Pragma("unroll") for (int c = 0; c < 2; c++) {                               \
      b01[n][c] = *(const bf16x8*)&Bs[CBUF][wc * 64 + n * 16 + lo]                \
                                         [((quad + 4 * c) ^ sw) * 8];             \
    }                                                                             \
  }
#define LDB23(CBUF)                                                               \
  _Pragma("unroll") for (int n = 0; n < 2; n++) {                                 \
    _Pragma("unroll") for (int c = 0; c < 2; c++) {                               \
      b23[n][c] = *(const bf16x8*)&Bs[CBUF][wc * 64 + 32 + n * 16 + lo]           \
                                         [((quad + 4 * c) ^ sw) * 8];             \
    }                                                                             \
  }
#define MFMA_Q(MB, AF, NB, BF)                                                    \
  __builtin_amdgcn_s_setprio(1);                                                  \
  _Pragma("unroll") for (int m = 0; m < 4; m++) {                                 \
    _Pragma("unroll") for (int n = 0; n < 2; n++) {                               \
      _Pragma("unroll") for (int c = 0; c < 2; c++) {                             \
        acc[(MB) + m][(NB) + n] = __builtin_amdgcn_mfma_f32_16x16x32_bf16(        \
            AF[m][c], BF[n][c], acc[(MB) + m][(NB) + n], 0, 0, 0);                \
      }                                                                           \
    }                                                                             \
  }                                                                               \
  __builtin_amdgcn_s_setprio(0);

// One sub-tile. STG: stage tile TT+2 into CBUF; VM: 8 steady / 0 tail / -1 none.
#define SUBTILE(CBUF, TT, STG, VM)                                                \
  {                                                                               \
    /* P0: in-phase reads (tile published at prev P3); MFMA L*b01; pf b23 */     \
    LDAL(CBUF);                                                                   \
    LDB01(CBUF);                                                                  \
    MFMA_Q(0, aL, 0, b01);                                                        \
    LDB23(CBUF);                                                                  \
    __builtin_amdgcn_s_barrier();                                                 \
    /* P1: MFMA L*b23 — all operands in registers, zero waits */                  \
    MFMA_Q(0, aL, 2, b23);                                                        \
    __builtin_amdgcn_s_barrier();                                                 \
    /* P2: stage B(TT+2) (B slots dead after P1 bar); read aH; MFMA H*b23 */     \
    if (STG) { STAGE_B(CBUF, (TT) + 2, 0); STAGE_B(CBUF, (TT) + 2, 1);            \
               STAGE_B(CBUF, (TT) + 2, 2); STAGE_B(CBUF, (TT) + 2, 3); }          \
    LDAH(CBUF);                                                                   \
    MFMA_Q(4, aH, 2, b23);                                                        \
    __builtin_amdgcn_s_barrier();                                                 \
    /* P3: stage A(TT+2) (A slots dead after P2 bar); MFMA H*b01; publish */     \
    if (STG) { STAGE_A(CBUF, (TT) + 2, 0); STAGE_A(CBUF, (TT) + 2, 1);            \
               STAGE_A(CBUF, (TT) + 2, 2); STAGE_A(CBUF, (TT) + 2, 3); }          \
    MFMA_Q(4, aH, 0, b01);                                                        \
    if ((VM) == 8) asm volatile("s_waitcnt vmcnt(8)" ::: "memory");               \
    else if ((VM) == 0) asm volatile("s_waitcnt vmcnt(0)" ::: "memory");          \
    __builtin_amdgcn_s_barrier();                                                 \
  }

  // main loop: s = 0..NT-3 (stage targets s+2 <= NT-1 all valid)
  for (int t = 0; t + 3 < NT; t += 2) {
    SUBTILE(0, t, 1, 8)
    SUBTILE(1, t + 1, 1, 8)
  }
  // tails: NT-2 (no stages; drain tile NT-1 fully), NT-1 (no stages/wait)
  SUBTILE(0, NT - 2, 0, 0)
  SUBTILE(1, NT - 1, 0, -1)

  if (EPI == 0) {
    // silu(gate) * value, lane-local pairing; ffin col base = tn/2
    const long colb = (tn >> 1);
    const long rowb = tm + wr * 128;
#pragma unroll
    for (int m = 0; m < 8; m++) {
#pragma unroll
      for (int np = 0; np < 2; np++) {
        const long col = colb + (wc * 2 + np) * 16 + lo;
#pragma unroll
        for (int r = 0; r < 4; r++) {
          const long row = rowb + m * 16 + quad * 4 + r;
          const float g  = acc[m][2 * np][r];
          const float v  = acc[m][2 * np + 1][r];
          const float s  = g / (1.f + __expf(-g));
          ((unsigned short*)Cout)[row * (long)FFP + col] = f2bf(s * v);
        }
      }
    }
  } else {
    const int f32m = *flagp;
    const long rowb = tm + wr * 128;
    const long colb = tn + wc * 64;
#pragma unroll
    for (int m = 0; m < 8; m++) {
#pragma unroll
      for (int n = 0; n < 4; n++) {
#pragma unroll
        for (int r = 0; r < 4; r++) {
          const long row = rowb + m * 16 + quad * 4 + r;
          const long col = colb + n * 16 + lo;
          float v = acc[m][n][r] + bf2f(res[row * (long)DM + col]);
          stout(Cout, outOff + row * (long)DM + col, f32m, v);
        }
      }
    }
  }
#undef STAGE_A
#undef STAGE_B
#undef LDAL
#undef LDAH
#undef LDB01
#undef LDB23
#undef MFMA_Q
#undef SUBTILE
}

// ---------------- RMSNorm: raw input variant (flag) --------------------------
__global__ void rmsnorm_x(const void* __restrict__ in, long elemOff,
                          const unsigned short* __restrict__ gamma,
                          unsigned short* __restrict__ out,
                          const int* __restrict__ flagp) {
  const int t    = blockIdx.x;
  const int lane = threadIdx.x;
  const int f32m = *flagp;
  float v[16];
  const long base = elemOff + (long)t * DM;
  if (f32m) {
    const float4* rp = (const float4*)((const float*)in + base);
#pragma unroll
    for (int j = 0; j < 4; j++) {
      float4 u     = rp[j * 64 + lane];
      v[j * 4 + 0] = u.x; v[j * 4 + 1] = u.y; v[j * 4 + 2] = u.z; v[j * 4 + 3] = u.w;
    }
  } else {
    const ushort4* rp = (const ushort4*)((const unsigned short*)in + base);
#pragma unroll
    for (int j = 0; j < 4; j++) {
      ushort4 u    = rp[j * 64 + lane];
      v[j * 4 + 0] = bf2f(u.x); v[j * 4 + 1] = bf2f(u.y);
      v[j * 4 + 2] = bf2f(u.z); v[j * 4 + 3] = bf2f(u.w);
    }
  }
  float s = 0.f;
#pragma unroll
  for (int i = 0; i < 16; i++) s = fmaf(v[i], v[i], s);
#pragma unroll
  for (int off = 32; off > 0; off >>= 1) s += __shfl_xor(s, off, 64);
  const float scale = 32.f / fmaxf(sqrtf(s), 1e-12f);
  ushort4* op       = (ushort4*)(out + (long)t * DM);
  const ushort4* gp = (const ushort4*)gamma;
#pragma unroll
  for (int j = 0; j < 4; j++) {
    ushort4 g = gp[j * 64 + lane];
    ushort4 o;
    o.x = f2bf(v[j * 4 + 0] * scale * (bf2f(g.x) + 1.f));
    o.y = f2bf(v[j * 4 + 1] * scale * (bf2f(g.y) + 1.f));
    o.z = f2bf(v[j * 4 + 2] * scale * (bf2f(g.z) + 1.f));
    o.w = f2bf(v[j * 4 + 3] * scale * (bf2f(g.w) + 1.f));
    op[j * 64 + lane] = o;
  }
}

// ---------------- RMSNorm (bf16 in/out) --------------------------------------
__global__ void rmsnorm_k(const unsigned short* __restrict__ in,
                          const unsigned short* __restrict__ gamma,
                          unsigned short* __restrict__ out) {
  const int t    = blockIdx.x;
  const int lane = threadIdx.x;
  float v[16];
  const ushort4* rp = (const ushort4*)(in + (long)t * DM);
#pragma unroll
  for (int j = 0; j < 4; j++) {
    ushort4 u    = rp[j * 64 + lane];
    v[j * 4 + 0] = bf2f(u.x); v[j * 4 + 1] = bf2f(u.y);
    v[j * 4 + 2] = bf2f(u.z); v[j * 4 + 3] = bf2f(u.w);
  }
  float s = 0.f;
#pragma unroll
  for (int i = 0; i < 16; i++) s = fmaf(v[i], v[i], s);
#pragma unroll
  for (int off = 32; off > 0; off >>= 1) s += __shfl_xor(s, off, 64);
  const float scale = 32.f / fmaxf(sqrtf(s), 1e-12f);
  ushort4* op       = (ushort4*)(out + (long)t * DM);
  const ushort4* gp = (const ushort4*)gamma;
#pragma unroll
  for (int j = 0; j < 4; j++) {
    ushort4 g = gp[j * 64 + lane];
    ushort4 o;
    o.x = f2bf(v[j * 4 + 0] * scale * (bf2f(g.x) + 1.f));
    o.y = f2bf(v[j * 4 + 1] * scale * (bf2f(g.y) + 1.f));
    o.z = f2bf(v[j * 4 + 2] * scale * (bf2f(g.z) + 1.f));
    o.w = f2bf(v[j * 4 + 3] * scale * (bf2f(g.w) + 1.f));
    op[j * 64 + lane] = o;
  }
}

// ---------------- causal depthwise conv K=4 ----------------------------------
__global__ void dwconv_k(const unsigned short* __restrict__ xn,
                         const unsigned short* __restrict__ dww,
                         const unsigned short* __restrict__ dwb,
                         unsigned short* __restrict__ y, int l0) {
  const int t = blockIdx.x;
  const int d = blockIdx.y * 256 + threadIdx.x;
  const int l = l0 + (t & (SEQL - 1));
  ushort4 w4  = ((const ushort4*)dww)[d];
  float wk[4] = {bf2f(w4.x), bf2f(w4.y), bf2f(w4.z), bf2f(w4.w)};
  float acc   = bf2f(dwb[d]);
#pragma unroll
  for (int k = 0; k < 4; k++) {
    const int ll = l + k - 3;
    if (ll >= 0) acc = fmaf(bf2f(xn[(long)(t + k - 3) * DM + d]), wk[k], acc);
  }
  y[(long)t * DM + d] = f2bf(acc);
}

// ---------------- scan --------------------------------------------------------
__device__ __forceinline__ void cv_compute(float gt, float& c, float& sg) {
  gt = fminf(fmaxf(gt, -40.f), 40.f);
  const float e  = __expf(-fabsf(gt));
  const float r  = 1.f / (1.f + e);
  const float rs = e * r;
  c  = (gt >= 0.f) ? rs : r;   // sigmoid(-gt)
  sg = (gt >= 0.f) ? r : rs;   // sigmoid(gt)
}
__device__ __forceinline__ float gfun(float hid) {
  hid = fminf(fmaxf(hid, -40.f), 40.f);
  if (hid >= 0.f) return hid + 0.5f;
  const float e = __expf(hid);
  return e / (1.f + e);
}

__global__ void scan_p1(const unsigned short* __restrict__ hg, float* __restrict__ cC,
                        float* __restrict__ cV, int chTot, int SL) {
  const int e = threadIdx.x, bh = blockIdx.y, cid = blockIdx.x;
  const int bL = bh >> 2, hh = bh & 3;
  long base = ((long)(bL * SL + cid * CHLEN)) * 3072 + hh * 768 + e;
  float C = 1.f, V = 0.f;
  for (int i = 0; i < CHLEN; i++) {
    const float hid = bf2f(hg[base]), gt = bf2f(hg[base + 384]);
    float c, sg; cv_compute(gt, c, sg);
    C *= c;
    V = fmaf(c, V, sg * gfun(hid));
    base += 3072;
  }
  const int idx = cid * chTot + bh * 384 + e;
  cC[idx] = C; cV[idx] = V;
}

__global__ void scan_p2(const float* __restrict__ cC, const float* __restrict__ cV,
                        float* __restrict__ hin, int chTot, int CHNp,
                        const float* __restrict__ hcarry, int useCarry) {
  const int ch = blockIdx.x * 384 + threadIdx.x;
  float h = useCarry ? hcarry[ch] : 0.f;
  for (int cid = 0; cid < CHNp; cid++) {
    const int idx = cid * chTot + ch;
    hin[idx] = h;
    h = fmaf(cC[idx], h, cV[idx]);
  }
}

__global__ void scan_p3(const unsigned short* __restrict__ hg, const float* __restrict__ hin,
                        unsigned short* __restrict__ hout, void* __restrict__ nh, long nhOff,
                        float* __restrict__ hcarry, int chTot, int SL, int CHNp,
                        int writeNh, const int* __restrict__ flagp) {
  const int e = threadIdx.x, bh = blockIdx.y, cid = blockIdx.x;
  const int bL = bh >> 2, hh = bh & 3;
  const long tok = (long)bL * SL + (long)cid * CHLEN;
  long base  = tok * 3072 + hh * 768 + e;
  long obase = tok * 1536 + hh * 384 + e;
  float h = hin[cid * chTot + bh * 384 + e];
  for (int i = 0; i < CHLEN; i++) {
    const float hid = bf2f(hg[base]), gt = bf2f(hg[base + 384]);
    float c, sg; cv_compute(gt, c, sg);
    h = fmaf(c, h, sg * gfun(hid));
    hout[obase] = f2bf(h);
    base += 3072; obase += 1536;
  }
  if (cid == CHNp - 1) {
    hcarry[bh * 384 + e] = h;
    if (writeNh) stout(nh, nhOff + bL * 1536 + hh * 384 + e, *flagp, h);
  }
}

// ---------------- weight conversion / transposes (flag-branching reads) -------
__global__ void cvt_k(const void* __restrict__ in, unsigned short* __restrict__ out,
                      int n, const int* __restrict__ flagp) {
  const int i = blockIdx.x * 256 + threadIdx.x;
  if (i < n) out[i] = f2bf(ldin(in, i, *flagp));
}
__global__ void tr_whg(const void* __restrict__ in, unsigned short* __restrict__ out,
                       const int* __restrict__ flagp) {
  const int idx = blockIdx.x * 256 + threadIdx.x;  // (h*768+n)*256+k
  const int k = idx & 255, n = (idx >> 8) % 768, h = idx / (768 * 256);
  out[idx] = f2bf(ldin(in, (long)(h * 256 + k) * 768 + n, *flagp));
}
__global__ void tr_wout(const void* __restrict__ in, unsigned short* __restrict__ out,
                        const int* __restrict__ flagp) {
  const int idx = blockIdx.x * 256 + threadIdx.x;  // (h*256+n)*384+k
  const int k = idx % 384, n = (idx / 384) & 255, h = idx / (384 * 256);
  out[idx] = f2bf(ldin(in, (long)(h * 384 + k) * 256 + n, *flagp));
}
__global__ void tr_wg(const void* __restrict__ in, unsigned short* __restrict__ out,
                      const int* __restrict__ flagp) {
  const int idx = blockIdx.x * 256 + threadIdx.x;  // n*1024+k, n<2816
  const int k = idx & 1023, n = idx >> 10;
  out[idx] = (n < FFN) ? f2bf(ldin(in, (long)k * FFN + n, *flagp)) : (unsigned short)0;
}
// interleaved gate/value: B row R -> tile=R>>8, pair=(R&255)>>5, sel=(R>>4)&1,
// col = tile*128 + pair*16 + (R&15); out[R][k] = W_{sel}[k][col] (0 if col>=FFN)
__global__ void tr_wgv(const void* __restrict__ wg, const void* __restrict__ wv,
                       unsigned short* __restrict__ out, const int* __restrict__ flagp) {
  const int idx = blockIdx.x * 256 + threadIdx.x;  // R*1024+k, R<5632
  const int k = idx & 1023, R = idx >> 10;
  const int tile = R >> 8, rb = R & 255;
  const int pair = rb >> 5, sel = (rb >> 4) & 1, r16 = rb & 15;
  const int col  = tile * 128 + pair * 16 + r16;
  const void* src = sel ? wv : wg;
  out[idx] = (col < FFN) ? f2bf(ldin(src, (long)k * FFN + col, *flagp)) : (unsigned short)0;
}
__global__ void tr_wfo(const void* __restrict__ in, unsigned short* __restrict__ out,
                       const int* __restrict__ flagp) {
  const int idx = blockIdx.x * 256 + threadIdx.x;  // n*2816+kk
  const int kk = idx % FFP, n = idx / FFP;
  out[idx] = (kk < FFN) ? f2bf(ldin(in, (long)kk * DM + n, *flagp)) : (unsigned short)0;
}

// ---------------- launch ------------------------------------------------------
extern "C" void kernel_launch(void* const* d_in, const int* in_sizes, int n_in,
                              void* d_out, int out_size, void* d_ws, size_t ws_size,
                              hipStream_t stream) {
  const void* x      = d_in[0];
  const void* dw_w   = d_in[1];
  const void* dw_b   = d_in[2];
  const void* pw_w   = d_in[3];  // [N=1024][K=1024] already
  const void* pw_b   = d_in[4];
  const void* conv_g = d_in[5];
  const void* gru_g  = d_in[6];
  const void* ff_g   = d_in[7];
  const void* w_hg   = d_in[8];
  const void* w_out  = d_in[9];
  const void* w_gate = d_in[10];
  const void* w_val  = d_in[11];
  const void* w_ffo  = d_in[12];

  // Pass size from ws_size (deterministic): need(MT) = 21,795,072 + MT*13,888.
  const long FIXED = 21795072L;
  int MT = 128;
  if      (ws_size >= (size_t)(FIXED + 16384L * 13888)) MT = 16384;
  else if (ws_size >= (size_t)(FIXED + 8192L * 13888))  MT = 8192;
  else if (ws_size >= (size_t)(FIXED + 4096L * 13888))  MT = 4096;
  else if (ws_size >= (size_t)(FIXED + 2048L * 13888))  MT = 2048;
  else if (ws_size >= (size_t)(FIXED + 1024L * 13888))  MT = 1024;
  else if (ws_size >= (size_t)(FIXED + 512L * 13888))   MT = 512;
  else if (ws_size >= (size_t)(FIXED + 256L * 13888))   MT = 256;

  const int SL    = (MT >= SEQL) ? SEQL : MT;
  const int nSeq  = MT / SL;
  const int CHNp  = SL / CHLEN;
  const int chTot = nSeq * 1536;
  const int big   = (MT >= 256);  // 256^2 pipelined path for the two FF GEMMs

  char* p = (char*)d_ws;
  unsigned short* whgT  = (unsigned short*)p; p += 1572864;
  unsigned short* woutT = (unsigned short*)p; p += 786432;
  unsigned short* wgT   = (unsigned short*)p; p += 5767168;
  unsigned short* wvT   = (unsigned short*)p; p += 5767168;
  unsigned short* wfoT  = (unsigned short*)p; p += 5767168;
  unsigned short* pwT   = (unsigned short*)p; p += 2097152;
  unsigned short* dwwB  = (unsigned short*)p; p += 8192;
  unsigned short* dwbB  = (unsigned short*)p; p += 2048;
  unsigned short* pwbB  = (unsigned short*)p; p += 2048;
  unsigned short* cgB   = (unsigned short*)p; p += 2048;
  unsigned short* ggB   = (unsigned short*)p; p += 2048;
  unsigned short* fgB   = (unsigned short*)p; p += 2048;
  int*            flag  = (int*)p;            p += 256;
  float*          hcarry= (float*)p;          p += 12288;
  float*          cC    = (float*)p;          p += (long)MT * 192;
  float*          cV    = (float*)p;          p += (long)MT * 192;
  float*          hin   = (float*)p;          p += (long)MT * 192;
  unsigned short* xnb   = (unsigned short*)p; p += 6144 + (long)MT * 2048;
  unsigned short* xc    = (unsigned short*)p; p += (long)MT * 2048;
  unsigned short* hbuf  = (unsigned short*)p; p += (long)MT * 3072;
  unsigned short* ybuf  = (unsigned short*)p;  // region R: ybuf / hg / ffin
  unsigned short* hg    = (unsigned short*)p;
  unsigned short* ffin  = (unsigned short*)p;
  unsigned short* xn    = xnb + 3 * DM;
  unsigned short* wgvT  = wgT;  // interleaved [5632][1024] spans wgT+wvT slots

  // dtype detection + weight conversion (once per call)
  detect_k<<<1, 256, 0, stream>>>((const unsigned short*)x, flag);
  tr_whg<<<3072, 256, 0, stream>>>(w_hg, whgT, flag);
  tr_wout<<<1536, 256, 0, stream>>>(w_out, woutT, flag);
  if (big) {
    tr_wgv<<<22528, 256, 0, stream>>>(w_gate, w_val, wgvT, flag);
  } else {
    tr_wg<<<11264, 256, 0, stream>>>(w_gate, wgT, flag);
    tr_wg<<<11264, 256, 0, stream>>>(w_val, wvT, flag);
  }
  tr_wfo<<<11264, 256, 0, stream>>>(w_ffo, wfoT, flag);
  cvt_k<<<4096, 256, 0, stream>>>(pw_w, pwT, 1048576, flag);
  cvt_k<<<16, 256, 0, stream>>>(dw_w, dwwB, 4096, flag);
  cvt_k<<<4, 256, 0, stream>>>(dw_b, dwbB, 1024, flag);
  cvt_k<<<4, 256, 0, stream>>>(pw_b, pwbB, 1024, flag);
  cvt_k<<<4, 256, 0, stream>>>(conv_g, cgB, 1024, flag);
  cvt_k<<<4, 256, 0, stream>>>(gru_g, ggB, 1024, flag);
  cvt_k<<<4, 256, 0, stream>>>(ff_g, fgB, 1024, flag);

  for (long t0 = 0; t0 < 16384; t0 += MT) {
    const int l0     = (int)(t0 & (SEQL - 1));
    const int P      = (l0 > 0) ? 3 : 0;
    const int seqEnd = (l0 + SL == SEQL);
    const long nhOff = NH_OFF + (t0 / SEQL) * 1536;

    // conv block: xc = pw(dwconv(rmsnorm(x))) + pw_b + x
    rmsnorm_x<<<MT + P, 64, 0, stream>>>(x, (t0 - P) * DM, cgB, xn - (long)P * DM, flag);
    dwconv_k<<<dim3(MT, 4), 256, 0, stream>>>(xn, dwwB, dwbB, ybuf, l0);
    gemm_bf16<1><<<dim3(8, MT / 128, 1), 256, 0, stream>>>(ybuf, DM, 0, pwT, 0, DM,
        xc, DM, 0, 0L, pwbB, x, DM, t0 * DM, flag);

    // GRU block
    rmsnorm_k<<<MT, 64, 0, stream>>>(xc, ggB, xn);
    gemm_bf16<0><<<dim3(6, MT / 128, 4), 256, 0, stream>>>(xn, DM, 256, whgT, 196608, 256,
        hg, 3072, 768, 0L, nullptr, nullptr, 0, 0L, nullptr);
    scan_p1<<<dim3(CHNp, nSeq * 4), 384, 0, stream>>>(hg, cC, cV, chTot, SL);
    scan_p2<<<nSeq * 4, 384, 0, stream>>>(cC, cV, hin, chTot, CHNp, hcarry, l0 > 0);
    scan_p3<<<dim3(CHNp, nSeq * 4), 384, 0, stream>>>(hg, hin, hbuf, d_out, nhOff,
        hcarry, chTot, SL, CHNp, seqEnd, flag);
    gemm_bf16<2><<<dim3(2, MT / 128, 4), 256, 0, stream>>>(hbuf, 1536, 384, woutT, 98304, 384,
        xc, DM, 256, 0L, nullptr, xc, DM, 0L, nullptr);

    // FF block
    rmsnorm_k<<<MT, 64, 0, stream>>>(xc, fgB, xn);
    if (big) {
      gemm256<0><<<dim3(22, MT / 256), 512, 0, stream>>>(xn, wgvT, DM,
          ffin, nullptr, 0L, nullptr);
      gemm256<1><<<dim3(4, MT / 256), 512, 0, stream>>>(ffin, wfoT, FFP,
          d_out, xc, t0 * DM, flag);
    } else {
      gemm_ff<<<dim3(22, MT / 128), 256, 0, stream>>>(xn, wgT, wvT, ffin);
      gemm_bf16<3><<<dim3(8, MT / 128, 1), 256, 0, stream>>>(ffin, FFP, 0, wfoT, 0, FFP,
          d_out, DM, 0, t0 * DM, nullptr, xc, DM, 0L, flag);
    }
  }
}